// Round 15
// baseline (221.505 us; speedup 1.0000x reference)
//
#include <hip/hip_runtime.h>

// GCN 2-layer. R15: gathers vectorized -- ushort4 row loads (8B/lane), 16 lanes/edge
// x 4 edges per wave-instruction (C=64) resp. 8 lanes/edge x 8 edges (C=32);
// shfl_xor butterfly combines edge subgroups. 4x fewer VMEM instructions per edge
// (R14 showed depth doesn't help -> CU-side VMEM instruction path is the limiter).

#define NBKT(n) (((n) + 127) >> 7)

__device__ inline float bf2f(unsigned short u) {
    union { unsigned int i; float f; } v;
    v.i = ((unsigned int)u) << 16;
    return v.f;
}
__device__ inline unsigned short f2bf(float f) {
    union { float f; unsigned int i; } v;
    v.f = f;
    unsigned int u = v.i;
    return (unsigned short)((u + 0x7fff + ((u >> 16) & 1)) >> 16);  // RTN-even
}

// ---------------- bucket histogram (R13 proven) ----------------
#define BH_CHUNK 4096
__global__ void __launch_bounds__(256) bhist_kernel(
        const int* __restrict__ dst, int E, int nbk, int* __restrict__ bcnt) {
    __shared__ int cnt[NBKT(100000)];
    const int t = threadIdx.x;
    const int beg = blockIdx.x * BH_CHUNK;
    const int end = min(E, beg + BH_CHUNK);
    for (int b = t; b < nbk; b += 256) cnt[b] = 0;
    __syncthreads();
    for (int i = beg + t; i < end; i += 256) atomicAdd(&cnt[dst[i] >> 7], 1);
    __syncthreads();
    for (int b = t; b < nbk; b += 256) {
        int c = cnt[b];
        if (c) atomicAdd(&bcnt[b], c);
    }
}

// ---------------- bucket offsets (R13 proven) ----------------
__global__ void bscan_kernel(const int* __restrict__ bcnt, int nbk, int E,
                             int* __restrict__ boffs, int* __restrict__ gcursor) {
    __shared__ int s[1024];
    const int t = threadIdx.x;
    int v = (t < nbk) ? bcnt[t] : 0;
    s[t] = v;
    __syncthreads();
    for (int off = 1; off < 1024; off <<= 1) {
        int x = (t >= off) ? s[t - off] : 0;
        __syncthreads();
        s[t] += x;
        __syncthreads();
    }
    if (t < nbk) {
        int excl = s[t] - v;
        boffs[t] = excl;
        gcursor[t] = excl;
    }
    if (t == 0) boffs[nbk] = E;
}

// ---------------- binfill (R8/R11 proven): entry = (src<<7)|(dst&127) ----------------
#define BF_CHUNK 4096
__global__ void __launch_bounds__(256) binfill_kernel(
        const int* __restrict__ src, const int* __restrict__ dst, int E, int nbk,
        int* __restrict__ gcursor, int* __restrict__ entries) {
    __shared__ int cnt[NBKT(100000)];
    __shared__ int gbase[NBKT(100000)];
    __shared__ int rank[NBKT(100000)];
    const int t = threadIdx.x;
    const int beg = blockIdx.x * BF_CHUNK;
    const int end = min(E, beg + BF_CHUNK);
    for (int b = t; b < nbk; b += 256) cnt[b] = 0;
    __syncthreads();
    for (int i = beg + t; i < end; i += 256) atomicAdd(&cnt[dst[i] >> 7], 1);
    __syncthreads();
    for (int b = t; b < nbk; b += 256) {
        int c = cnt[b];
        gbase[b] = c ? atomicAdd(&gcursor[b], c) : 0;
        rank[b] = 0;
    }
    __syncthreads();
    for (int i = beg + t; i < end; i += 256) {
        int d = dst[i];
        int b = d >> 7;
        int r = atomicAdd(&rank[b], 1);
        entries[gbase[b] + r] = (src[i] << 7) | (d & 127);
    }
}

// ---------------- bucket2csr (R9 proven) + dinv emission (R13) ----------------
__global__ void __launch_bounds__(256) bucket2csr_kernel(
        const int* __restrict__ entries, const int* __restrict__ boffs, int nbk,
        int* __restrict__ offs, int* __restrict__ csr_src, float* __restrict__ dinv,
        int N, int E) {
    __shared__ int cnt[128];
    __shared__ int s[128];
    __shared__ int rank[128];
    const int t = threadIdx.x;
    const int b = blockIdx.x;
    const int beg = boffs[b];
    const int end = boffs[b + 1];
    if (t < 128) { cnt[t] = 0; rank[t] = 0; }
    __syncthreads();
    for (int i = beg + t; i < end; i += 256) atomicAdd(&cnt[entries[i] & 127], 1);
    __syncthreads();
    if (t < 128) s[t] = cnt[t];
    __syncthreads();
    for (int off = 1; off < 128; off <<= 1) {
        int x = 0;
        if (t < 128 && t >= off) x = s[t - off];
        __syncthreads();
        if (t < 128) s[t] += x;
        __syncthreads();
    }
    const int node0 = b * 128;
    if (t < 128 && node0 + t < N) {
        offs[node0 + t] = beg + s[t] - cnt[t];
        dinv[node0 + t] = rsqrtf((float)cnt[t] + 1.0f);  // +1 = self-loop
    }
    if (b == 0 && t == 0) offs[N] = E;
    __syncthreads();
    for (int i = beg + t; i < end; i += 256) {
        int e = entries[i];
        int d = e & 127;
        int r = atomicAdd(&rank[d], 1);
        csr_src[beg + s[d] - cnt[d] + r] = (int)((unsigned)e >> 7);
    }
}

// ---------------- LDS-tiled GEMM (R6 proven), bf16-out option ----------------
#define FMA4(ACC, AV, WV) \
    ACC.x += (AV) * (WV).x; ACC.y += (AV) * (WV).y; ACC.z += (AV) * (WV).z; ACC.w += (AV) * (WV).w;

template <int K, int C, int BR, bool BF16OUT>
__global__ void __launch_bounds__(256) gemm_tile_kernel(
        const float* __restrict__ A, const float* __restrict__ W,
        const float* __restrict__ dinv, void* __restrict__ outv, int N) {
    constexpr int F4R = K / 4;
    constexpr int CG = C / 4;
    static_assert(256 / CG * 4 == BR, "geometry");
    __shared__ float Wl[K * C];
    __shared__ float Al[BR * K];

    const int t = threadIdx.x;
    for (int i = t; i < K * C / 4; i += 256) ((float4*)Wl)[i] = ((const float4*)W)[i];
    const int row0 = blockIdx.x * BR;
    for (int i = t; i < BR * F4R; i += 256) {
        int r = i / F4R, k4 = i % F4R;
        float4 v = make_float4(0.f, 0.f, 0.f, 0.f);
        if (row0 + r < N) v = ((const float4*)(A + (size_t)(row0 + r) * K))[k4];
        *(float4*)(Al + r * K + k4 * 4) = v;
    }
    __syncthreads();

    const int c0 = (t % CG) * 4;
    const int r0 = (t / CG) * 4;
    const float* Ab = Al + r0 * K;

    float4 acc0 = {0, 0, 0, 0}, acc1 = {0, 0, 0, 0}, acc2 = {0, 0, 0, 0}, acc3 = {0, 0, 0, 0};

#pragma unroll 2
    for (int k4 = 0; k4 < K / 4; ++k4) {
        float4 a0 = *(const float4*)(Ab + 0 * K + k4 * 4);
        float4 a1 = *(const float4*)(Ab + 1 * K + k4 * 4);
        float4 a2 = *(const float4*)(Ab + 2 * K + k4 * 4);
        float4 a3 = *(const float4*)(Ab + 3 * K + k4 * 4);
        float4 w0 = *(const float4*)(Wl + (k4 * 4 + 0) * C + c0);
        float4 w1 = *(const float4*)(Wl + (k4 * 4 + 1) * C + c0);
        float4 w2 = *(const float4*)(Wl + (k4 * 4 + 2) * C + c0);
        float4 w3 = *(const float4*)(Wl + (k4 * 4 + 3) * C + c0);
        FMA4(acc0, a0.x, w0) FMA4(acc1, a1.x, w0) FMA4(acc2, a2.x, w0) FMA4(acc3, a3.x, w0)
        FMA4(acc0, a0.y, w1) FMA4(acc1, a1.y, w1) FMA4(acc2, a2.y, w1) FMA4(acc3, a3.y, w1)
        FMA4(acc0, a0.z, w2) FMA4(acc1, a1.z, w2) FMA4(acc2, a2.z, w2) FMA4(acc3, a3.z, w2)
        FMA4(acc0, a0.w, w3) FMA4(acc1, a1.w, w3) FMA4(acc2, a2.w, w3) FMA4(acc3, a3.w, w3)
    }

    const int row = row0 + r0;
#pragma unroll
    for (int i = 0; i < 4; ++i) {
        int rr = row + i;
        if (rr < N) {
            float d = dinv[rr];
            float4 fr = (i == 0) ? acc0 : (i == 1) ? acc1 : (i == 2) ? acc2 : acc3;
            fr.x *= d; fr.y *= d; fr.z *= d; fr.w *= d;
            if (BF16OUT) {
                ushort4 o;
                o.x = f2bf(fr.x); o.y = f2bf(fr.y); o.z = f2bf(fr.z); o.w = f2bf(fr.w);
                *(ushort4*)((unsigned short*)outv + (size_t)rr * C + c0) = o;
            } else {
                *(float4*)((float*)outv + (size_t)rr * C + c0) = fr;
            }
        }
    }
}

// ---------------- gather C=64: 16 lanes/edge, 4 edges per row-load instruction -------
// lane = sub*16 + f4 : sub picks edge slot, f4 picks feature group (4 feats, ushort4).
// Butterfly over sub bits (xor 16, 32) combines the 4 edge-slot partials.
template <bool RELU>
__global__ void __launch_bounds__(256) gather64_kernel(
        const unsigned short* __restrict__ hs, const float* __restrict__ dinv,
        const int* __restrict__ offs, const int* __restrict__ csr_src,
        const float* __restrict__ b, float* __restrict__ out, int N) {
    const int lane = threadIdx.x & 63;
    const int d = blockIdx.x * 4 + (threadIdx.x >> 6);  // one node per wave
    if (d >= N) return;
    const int sub = lane >> 4;   // 0..3
    const int f4 = lane & 15;    // feature group
    const int beg = offs[d];
    const int end = offs[d + 1];
    float4 acc = {0.f, 0.f, 0.f, 0.f};
    for (int j = beg; j < end; j += 8) {  // 2 predicated rounds of 4 edges
        const int rem = end - j;
        if (sub < rem) {
            int s = csr_src[j + sub];
            ushort4 u = *(const ushort4*)(hs + (size_t)s * 64 + f4 * 4);
            acc.x += bf2f(u.x); acc.y += bf2f(u.y); acc.z += bf2f(u.z); acc.w += bf2f(u.w);
        }
        if (sub + 4 < rem) {
            int s = csr_src[j + 4 + sub];
            ushort4 u = *(const ushort4*)(hs + (size_t)s * 64 + f4 * 4);
            acc.x += bf2f(u.x); acc.y += bf2f(u.y); acc.z += bf2f(u.z); acc.w += bf2f(u.w);
        }
    }
    // combine the 4 edge-slot partials (uniform, whole wave active)
    acc.x += __shfl_xor(acc.x, 16); acc.y += __shfl_xor(acc.y, 16);
    acc.z += __shfl_xor(acc.z, 16); acc.w += __shfl_xor(acc.w, 16);
    acc.x += __shfl_xor(acc.x, 32); acc.y += __shfl_xor(acc.y, 32);
    acc.z += __shfl_xor(acc.z, 32); acc.w += __shfl_xor(acc.w, 32);
    // self-loop + bias (+relu)
    ushort4 us = *(const ushort4*)(hs + (size_t)d * 64 + f4 * 4);
    float4 bv = ((const float4*)b)[f4];
    const float di = dinv[d];
    float4 r;
    r.x = (acc.x + bf2f(us.x)) * di + bv.x;
    r.y = (acc.y + bf2f(us.y)) * di + bv.y;
    r.z = (acc.z + bf2f(us.z)) * di + bv.z;
    r.w = (acc.w + bf2f(us.w)) * di + bv.w;
    if (RELU) {
        r.x = fmaxf(r.x, 0.f); r.y = fmaxf(r.y, 0.f);
        r.z = fmaxf(r.z, 0.f); r.w = fmaxf(r.w, 0.f);
    }
    if (lane < 16) *(float4*)(out + (size_t)d * 64 + f4 * 4) = r;
}

// ---------------- gather C=32: 8 lanes/edge, 8 edges per row-load instruction --------
__global__ void __launch_bounds__(256) gather32_kernel(
        const unsigned short* __restrict__ hs, const float* __restrict__ dinv,
        const int* __restrict__ offs, const int* __restrict__ csr_src,
        const float* __restrict__ b, float* __restrict__ out, int N) {
    const int lane = threadIdx.x & 63;
    const int d = blockIdx.x * 4 + (threadIdx.x >> 6);  // one node per wave
    if (d >= N) return;
    const int sub = lane >> 3;   // 0..7
    const int f4 = lane & 7;     // feature group (4 feats of 32)
    const int beg = offs[d];
    const int end = offs[d + 1];
    float4 acc = {0.f, 0.f, 0.f, 0.f};
    for (int j = beg; j < end; j += 16) {  // 2 predicated rounds of 8 edges
        const int rem = end - j;
        if (sub < rem) {
            int s = csr_src[j + sub];
            ushort4 u = *(const ushort4*)(hs + (size_t)s * 32 + f4 * 4);
            acc.x += bf2f(u.x); acc.y += bf2f(u.y); acc.z += bf2f(u.z); acc.w += bf2f(u.w);
        }
        if (sub + 8 < rem) {
            int s = csr_src[j + 8 + sub];
            ushort4 u = *(const ushort4*)(hs + (size_t)s * 32 + f4 * 4);
            acc.x += bf2f(u.x); acc.y += bf2f(u.y); acc.z += bf2f(u.z); acc.w += bf2f(u.w);
        }
    }
    // combine the 8 edge-slot partials
    acc.x += __shfl_xor(acc.x, 8);  acc.y += __shfl_xor(acc.y, 8);
    acc.z += __shfl_xor(acc.z, 8);  acc.w += __shfl_xor(acc.w, 8);
    acc.x += __shfl_xor(acc.x, 16); acc.y += __shfl_xor(acc.y, 16);
    acc.z += __shfl_xor(acc.z, 16); acc.w += __shfl_xor(acc.w, 16);
    acc.x += __shfl_xor(acc.x, 32); acc.y += __shfl_xor(acc.y, 32);
    acc.z += __shfl_xor(acc.z, 32); acc.w += __shfl_xor(acc.w, 32);
    // self-loop + bias
    ushort4 us = *(const ushort4*)(hs + (size_t)d * 32 + f4 * 4);
    float4 bv = ((const float4*)b)[f4];
    const float di = dinv[d];
    float4 r;
    r.x = (acc.x + bf2f(us.x)) * di + bv.x;
    r.y = (acc.y + bf2f(us.y)) * di + bv.y;
    r.z = (acc.z + bf2f(us.z)) * di + bv.z;
    r.w = (acc.w + bf2f(us.w)) * di + bv.w;
    if (lane < 8) *(float4*)(out + (size_t)d * 32 + f4 * 4) = r;
}

extern "C" void kernel_launch(void* const* d_in, const int* in_sizes, int n_in,
                              void* d_out, int out_size, void* d_ws, size_t ws_size,
                              hipStream_t stream) {
    const float* x = (const float*)d_in[0];
    const int* ei = (const int*)d_in[1];
    const float* W1 = (const float*)d_in[2];
    const float* b1 = (const float*)d_in[3];
    const float* W2 = (const float*)d_in[4];
    const float* b2 = (const float*)d_in[5];

    const int N = in_sizes[0] / 128;  // 100000
    const int E = in_sizes[1] / 2;    // 1600000
    const int* src = ei;
    const int* dst = ei + E;
    const int nbk = NBKT(N);          // 782 buckets of 128 dst nodes

    // workspace layout (4-byte units unless noted)
    int* bcnt = (int*)d_ws;                            // nbk (pad 1024)
    int* boffs = bcnt + 1024;                          // nbk+1 (pad 1024)
    int* gcursor = boffs + 1024;                       // nbk (pad 1024)
    float* dinv = (float*)(gcursor + 1024);            // N
    int* offs = (int*)(dinv + ((N + 255) & ~255));     // N+1
    int* entries = offs + ((N + 1 + 255) & ~255);      // E
    int* csr_src = entries + ((E + 255) & ~255);       // E
    unsigned short* h1s = (unsigned short*)(csr_src + ((E + 255) & ~255));  // N*64 bf16
    float* h2 = (float*)(h1s + (size_t)N * 64);        // N*64 fp32
    unsigned short* h3s = h1s;                         // reuse (N*32 bf16)
    float* out = (float*)d_out;

    // 1) bucket histogram -> offsets
    hipMemsetAsync(bcnt, 0, 1024 * 4, stream);
    bhist_kernel<<<(E + BH_CHUNK - 1) / BH_CHUNK, 256, 0, stream>>>(dst, E, nbk, bcnt);
    bscan_kernel<<<1, 1024, 0, stream>>>(bcnt, nbk, E, boffs, gcursor);

    // 2) two-phase node-exact CSR build (bucket2csr also emits dinv)
    binfill_kernel<<<(E + BF_CHUNK - 1) / BF_CHUNK, 256, 0, stream>>>(src, dst, E, nbk, gcursor, entries);
    bucket2csr_kernel<<<nbk, 256, 0, stream>>>(entries, boffs, nbk, offs, csr_src, dinv, N, E);

    // 3) h1s = bf16((x @ W1) * dinv)
    gemm_tile_kernel<128, 64, 64, true><<<(N + 63) / 64, 256, 0, stream>>>(x, W1, dinv, h1s, N);

    // 4) h2 = relu(dinv*(gather h1s) + b1)   (fp32)
    gather64_kernel<true><<<(N + 3) / 4, 256, 0, stream>>>(h1s, dinv, offs, csr_src, b1, h2, N);

    // 5) h3s = bf16((h2 @ W2) * dinv)
    gemm_tile_kernel<64, 32, 128, true><<<(N + 127) / 128, 256, 0, stream>>>(h2, W2, dinv, h3s, N);

    // 6) out = dinv*(gather h3s) + b2   (fp32)
    gather32_kernel<<<(N + 3) / 4, 256, 0, stream>>>(h3s, dinv, offs, csr_src, b2, out, N);
}

// Round 16
// 220.730 us; speedup vs baseline: 1.0035x; 1.0035x over previous
//
#include <hip/hip_runtime.h>

// GCN 2-layer. R16: gathers reverted to R14 (proven best, 53us); GEMM2 fused into
// gather64's epilogue (W2 half-columns in 32 regs/lane, shfl-broadcast matmul,
// shfl_xor(32) combine) -> gemm2 dispatch + 51MB h2 round-trip eliminated.

#define NBKT(n) (((n) + 127) >> 7)

__device__ inline float bf2f(unsigned short u) {
    union { unsigned int i; float f; } v;
    v.i = ((unsigned int)u) << 16;
    return v.f;
}
__device__ inline unsigned short f2bf(float f) {
    union { float f; unsigned int i; } v;
    v.f = f;
    unsigned int u = v.i;
    return (unsigned short)((u + 0x7fff + ((u >> 16) & 1)) >> 16);  // RTN-even
}

// ---------------- bucket histogram (R13 proven) ----------------
#define BH_CHUNK 4096
__global__ void __launch_bounds__(256) bhist_kernel(
        const int* __restrict__ dst, int E, int nbk, int* __restrict__ bcnt) {
    __shared__ int cnt[NBKT(100000)];
    const int t = threadIdx.x;
    const int beg = blockIdx.x * BH_CHUNK;
    const int end = min(E, beg + BH_CHUNK);
    for (int b = t; b < nbk; b += 256) cnt[b] = 0;
    __syncthreads();
    for (int i = beg + t; i < end; i += 256) atomicAdd(&cnt[dst[i] >> 7], 1);
    __syncthreads();
    for (int b = t; b < nbk; b += 256) {
        int c = cnt[b];
        if (c) atomicAdd(&bcnt[b], c);
    }
}

// ---------------- bucket offsets (R13 proven) ----------------
__global__ void bscan_kernel(const int* __restrict__ bcnt, int nbk, int E,
                             int* __restrict__ boffs, int* __restrict__ gcursor) {
    __shared__ int s[1024];
    const int t = threadIdx.x;
    int v = (t < nbk) ? bcnt[t] : 0;
    s[t] = v;
    __syncthreads();
    for (int off = 1; off < 1024; off <<= 1) {
        int x = (t >= off) ? s[t - off] : 0;
        __syncthreads();
        s[t] += x;
        __syncthreads();
    }
    if (t < nbk) {
        int excl = s[t] - v;
        boffs[t] = excl;
        gcursor[t] = excl;
    }
    if (t == 0) boffs[nbk] = E;
}

// ---------------- binfill (R8/R11 proven): entry = (src<<7)|(dst&127) ----------------
#define BF_CHUNK 4096
__global__ void __launch_bounds__(256) binfill_kernel(
        const int* __restrict__ src, const int* __restrict__ dst, int E, int nbk,
        int* __restrict__ gcursor, int* __restrict__ entries) {
    __shared__ int cnt[NBKT(100000)];
    __shared__ int gbase[NBKT(100000)];
    __shared__ int rank[NBKT(100000)];
    const int t = threadIdx.x;
    const int beg = blockIdx.x * BF_CHUNK;
    const int end = min(E, beg + BF_CHUNK);
    for (int b = t; b < nbk; b += 256) cnt[b] = 0;
    __syncthreads();
    for (int i = beg + t; i < end; i += 256) atomicAdd(&cnt[dst[i] >> 7], 1);
    __syncthreads();
    for (int b = t; b < nbk; b += 256) {
        int c = cnt[b];
        gbase[b] = c ? atomicAdd(&gcursor[b], c) : 0;
        rank[b] = 0;
    }
    __syncthreads();
    for (int i = beg + t; i < end; i += 256) {
        int d = dst[i];
        int b = d >> 7;
        int r = atomicAdd(&rank[b], 1);
        entries[gbase[b] + r] = (src[i] << 7) | (d & 127);
    }
}

// ---------------- bucket2csr (R9 proven) + dinv emission (R13) ----------------
__global__ void __launch_bounds__(256) bucket2csr_kernel(
        const int* __restrict__ entries, const int* __restrict__ boffs, int nbk,
        int* __restrict__ offs, int* __restrict__ csr_src, float* __restrict__ dinv,
        int N, int E) {
    __shared__ int cnt[128];
    __shared__ int s[128];
    __shared__ int rank[128];
    const int t = threadIdx.x;
    const int b = blockIdx.x;
    const int beg = boffs[b];
    const int end = boffs[b + 1];
    if (t < 128) { cnt[t] = 0; rank[t] = 0; }
    __syncthreads();
    for (int i = beg + t; i < end; i += 256) atomicAdd(&cnt[entries[i] & 127], 1);
    __syncthreads();
    if (t < 128) s[t] = cnt[t];
    __syncthreads();
    for (int off = 1; off < 128; off <<= 1) {
        int x = 0;
        if (t < 128 && t >= off) x = s[t - off];
        __syncthreads();
        if (t < 128) s[t] += x;
        __syncthreads();
    }
    const int node0 = b * 128;
    if (t < 128 && node0 + t < N) {
        offs[node0 + t] = beg + s[t] - cnt[t];
        dinv[node0 + t] = rsqrtf((float)cnt[t] + 1.0f);  // +1 = self-loop
    }
    if (b == 0 && t == 0) offs[N] = E;
    __syncthreads();
    for (int i = beg + t; i < end; i += 256) {
        int e = entries[i];
        int d = e & 127;
        int r = atomicAdd(&rank[d], 1);
        csr_src[beg + s[d] - cnt[d] + r] = (int)((unsigned)e >> 7);
    }
}

// ---------------- LDS-tiled GEMM (R6 proven), bf16 out ----------------
#define FMA4(ACC, AV, WV) \
    ACC.x += (AV) * (WV).x; ACC.y += (AV) * (WV).y; ACC.z += (AV) * (WV).z; ACC.w += (AV) * (WV).w;

template <int K, int C, int BR, bool BF16OUT>
__global__ void __launch_bounds__(256) gemm_tile_kernel(
        const float* __restrict__ A, const float* __restrict__ W,
        const float* __restrict__ dinv, void* __restrict__ outv, int N) {
    constexpr int F4R = K / 4;
    constexpr int CG = C / 4;
    static_assert(256 / CG * 4 == BR, "geometry");
    __shared__ float Wl[K * C];
    __shared__ float Al[BR * K];

    const int t = threadIdx.x;
    for (int i = t; i < K * C / 4; i += 256) ((float4*)Wl)[i] = ((const float4*)W)[i];
    const int row0 = blockIdx.x * BR;
    for (int i = t; i < BR * F4R; i += 256) {
        int r = i / F4R, k4 = i % F4R;
        float4 v = make_float4(0.f, 0.f, 0.f, 0.f);
        if (row0 + r < N) v = ((const float4*)(A + (size_t)(row0 + r) * K))[k4];
        *(float4*)(Al + r * K + k4 * 4) = v;
    }
    __syncthreads();

    const int c0 = (t % CG) * 4;
    const int r0 = (t / CG) * 4;
    const float* Ab = Al + r0 * K;

    float4 acc0 = {0, 0, 0, 0}, acc1 = {0, 0, 0, 0}, acc2 = {0, 0, 0, 0}, acc3 = {0, 0, 0, 0};

#pragma unroll 2
    for (int k4 = 0; k4 < K / 4; ++k4) {
        float4 a0 = *(const float4*)(Ab + 0 * K + k4 * 4);
        float4 a1 = *(const float4*)(Ab + 1 * K + k4 * 4);
        float4 a2 = *(const float4*)(Ab + 2 * K + k4 * 4);
        float4 a3 = *(const float4*)(Ab + 3 * K + k4 * 4);
        float4 w0 = *(const float4*)(Wl + (k4 * 4 + 0) * C + c0);
        float4 w1 = *(const float4*)(Wl + (k4 * 4 + 1) * C + c0);
        float4 w2 = *(const float4*)(Wl + (k4 * 4 + 2) * C + c0);
        float4 w3 = *(const float4*)(Wl + (k4 * 4 + 3) * C + c0);
        FMA4(acc0, a0.x, w0) FMA4(acc1, a1.x, w0) FMA4(acc2, a2.x, w0) FMA4(acc3, a3.x, w0)
        FMA4(acc0, a0.y, w1) FMA4(acc1, a1.y, w1) FMA4(acc2, a2.y, w1) FMA4(acc3, a3.y, w1)
        FMA4(acc0, a0.z, w2) FMA4(acc1, a1.z, w2) FMA4(acc2, a2.z, w2) FMA4(acc3, a3.z, w2)
        FMA4(acc0, a0.w, w3) FMA4(acc1, a1.w, w3) FMA4(acc2, a2.w, w3) FMA4(acc3, a3.w, w3)
    }

    const int row = row0 + r0;
#pragma unroll
    for (int i = 0; i < 4; ++i) {
        int rr = row + i;
        if (rr < N) {
            float d = dinv[rr];
            float4 fr = (i == 0) ? acc0 : (i == 1) ? acc1 : (i == 2) ? acc2 : acc3;
            fr.x *= d; fr.y *= d; fr.z *= d; fr.w *= d;
            if (BF16OUT) {
                ushort4 o;
                o.x = f2bf(fr.x); o.y = f2bf(fr.y); o.z = f2bf(fr.z); o.w = f2bf(fr.w);
                *(ushort4*)((unsigned short*)outv + (size_t)rr * C + c0) = o;
            } else {
                *(float4*)((float*)outv + (size_t)rr * C + c0) = fr;
            }
        }
    }
}

// ---------------- fused gather(h1s) + relu + GEMM2: h3s = bf16(relu-gathered @ W2 * dinv)
// One node per wave (R14 gather structure, 16 edges in flight). After the reduction,
// lane = feature k of h2. W2 half-columns live in 32 regs/lane (full unroll);
// matmul via 32 shfl broadcasts per half-wave + xor(32) combine.
#define G64_LOAD(SS) bf2f(hs[(size_t)(SS) * 64 + lane])
__global__ void __launch_bounds__(256) gather64_gemm2_kernel(
        const unsigned short* __restrict__ hs, const float* __restrict__ dinv,
        const int* __restrict__ offs, const int* __restrict__ csr_src,
        const float* __restrict__ b1, const float* __restrict__ W2,
        unsigned short* __restrict__ h3s, int N) {
    const int lane = threadIdx.x & 63;
    const int d = blockIdx.x * 4 + (threadIdx.x >> 6);  // wave-uniform node
    if (d >= N) return;
    const int hf = lane >> 5;   // k-half (0: k=0..31, 1: k=32..63)
    const int c = lane & 31;    // output column
    float w2r[32];
#pragma unroll
    for (int k = 0; k < 32; ++k) w2r[k] = W2[(hf * 32 + k) * 32 + c];

    const int beg = offs[d];
    const int end = offs[d + 1];
    float acc0 = G64_LOAD(d);  // self-loop
    float acc1 = 0.f, acc2 = 0.f, acc3 = 0.f;
    int j = beg;
    for (; j + 15 < end; j += 16) {
        int s0 = csr_src[j + 0], s1 = csr_src[j + 1], s2 = csr_src[j + 2], s3 = csr_src[j + 3];
        int s4 = csr_src[j + 4], s5 = csr_src[j + 5], s6 = csr_src[j + 6], s7 = csr_src[j + 7];
        int s8 = csr_src[j + 8], s9 = csr_src[j + 9], sa = csr_src[j + 10], sb = csr_src[j + 11];
        int sc = csr_src[j + 12], sd = csr_src[j + 13], se = csr_src[j + 14], sf = csr_src[j + 15];
        float v0 = G64_LOAD(s0), v1 = G64_LOAD(s1), v2 = G64_LOAD(s2), v3 = G64_LOAD(s3);
        float v4 = G64_LOAD(s4), v5 = G64_LOAD(s5), v6 = G64_LOAD(s6), v7 = G64_LOAD(s7);
        float v8 = G64_LOAD(s8), v9 = G64_LOAD(s9), va = G64_LOAD(sa), vb = G64_LOAD(sb);
        float vc = G64_LOAD(sc), vd = G64_LOAD(sd), ve = G64_LOAD(se), vf = G64_LOAD(sf);
        acc0 += v0; acc1 += v1; acc2 += v2; acc3 += v3;
        acc0 += v4; acc1 += v5; acc2 += v6; acc3 += v7;
        acc0 += v8; acc1 += v9; acc2 += va; acc3 += vb;
        acc0 += vc; acc1 += vd; acc2 += ve; acc3 += vf;
    }
    if (j + 7 < end) {
        int s0 = csr_src[j + 0], s1 = csr_src[j + 1], s2 = csr_src[j + 2], s3 = csr_src[j + 3];
        int s4 = csr_src[j + 4], s5 = csr_src[j + 5], s6 = csr_src[j + 6], s7 = csr_src[j + 7];
        float v0 = G64_LOAD(s0), v1 = G64_LOAD(s1), v2 = G64_LOAD(s2), v3 = G64_LOAD(s3);
        float v4 = G64_LOAD(s4), v5 = G64_LOAD(s5), v6 = G64_LOAD(s6), v7 = G64_LOAD(s7);
        acc0 += v0; acc1 += v1; acc2 += v2; acc3 += v3;
        acc0 += v4; acc1 += v5; acc2 += v6; acc3 += v7;
        j += 8;
    }
    if (j + 3 < end) {
        int s0 = csr_src[j + 0], s1 = csr_src[j + 1], s2 = csr_src[j + 2], s3 = csr_src[j + 3];
        acc0 += G64_LOAD(s0); acc1 += G64_LOAD(s1); acc2 += G64_LOAD(s2); acc3 += G64_LOAD(s3);
        j += 4;
    }
    for (; j < end; ++j) acc0 += G64_LOAD(csr_src[j]);

    const float dv = dinv[d];
    float h2v = fmaxf(((acc0 + acc1) + (acc2 + acc3)) * dv + b1[lane], 0.f);  // h2[lane]

    // h3[c] = sum_k h2[k] * W2[k][c], split across half-waves (all 64 lanes converged)
    float sum = 0.f;
#pragma unroll
    for (int k = 0; k < 32; ++k) {
        float hv = __shfl(h2v, hf * 32 + k);
        sum += hv * w2r[k];
    }
    sum += __shfl_xor(sum, 32);
    if (lane < 32) h3s[(size_t)d * 32 + c] = f2bf(sum * dv);
}

// ---------------- gather C=32 (R14 proven): 2 nodes/wave, 16 edges in flight ---------
#define G32_LOAD(SS) bf2f(hs[(size_t)(SS) * 32 + lane])
__global__ void __launch_bounds__(256) gather32_kernel(
        const unsigned short* __restrict__ hs, const float* __restrict__ dinv,
        const int* __restrict__ offs, const int* __restrict__ csr_src,
        const float* __restrict__ b, float* __restrict__ out, int N) {
    const int lane = threadIdx.x & 31;
    const int d = blockIdx.x * 8 + (threadIdx.x >> 5);
    if (d >= N) return;
    const int beg = offs[d];
    const int end = offs[d + 1];
    float acc0 = G32_LOAD(d);  // self-loop
    float acc1 = 0.f, acc2 = 0.f, acc3 = 0.f;
    int j = beg;
    for (; j + 15 < end; j += 16) {
        int s0 = csr_src[j + 0], s1 = csr_src[j + 1], s2 = csr_src[j + 2], s3 = csr_src[j + 3];
        int s4 = csr_src[j + 4], s5 = csr_src[j + 5], s6 = csr_src[j + 6], s7 = csr_src[j + 7];
        int s8 = csr_src[j + 8], s9 = csr_src[j + 9], sa = csr_src[j + 10], sb = csr_src[j + 11];
        int sc = csr_src[j + 12], sd = csr_src[j + 13], se = csr_src[j + 14], sf = csr_src[j + 15];
        float v0 = G32_LOAD(s0), v1 = G32_LOAD(s1), v2 = G32_LOAD(s2), v3 = G32_LOAD(s3);
        float v4 = G32_LOAD(s4), v5 = G32_LOAD(s5), v6 = G32_LOAD(s6), v7 = G32_LOAD(s7);
        float v8 = G32_LOAD(s8), v9 = G32_LOAD(s9), va = G32_LOAD(sa), vb = G32_LOAD(sb);
        float vc = G32_LOAD(sc), vd = G32_LOAD(sd), ve = G32_LOAD(se), vf = G32_LOAD(sf);
        acc0 += v0; acc1 += v1; acc2 += v2; acc3 += v3;
        acc0 += v4; acc1 += v5; acc2 += v6; acc3 += v7;
        acc0 += v8; acc1 += v9; acc2 += va; acc3 += vb;
        acc0 += vc; acc1 += vd; acc2 += ve; acc3 += vf;
    }
    if (j + 7 < end) {
        int s0 = csr_src[j + 0], s1 = csr_src[j + 1], s2 = csr_src[j + 2], s3 = csr_src[j + 3];
        int s4 = csr_src[j + 4], s5 = csr_src[j + 5], s6 = csr_src[j + 6], s7 = csr_src[j + 7];
        float v0 = G32_LOAD(s0), v1 = G32_LOAD(s1), v2 = G32_LOAD(s2), v3 = G32_LOAD(s3);
        float v4 = G32_LOAD(s4), v5 = G32_LOAD(s5), v6 = G32_LOAD(s6), v7 = G32_LOAD(s7);
        acc0 += v0; acc1 += v1; acc2 += v2; acc3 += v3;
        acc0 += v4; acc1 += v5; acc2 += v6; acc3 += v7;
        j += 8;
    }
    if (j + 3 < end) {
        int s0 = csr_src[j + 0], s1 = csr_src[j + 1], s2 = csr_src[j + 2], s3 = csr_src[j + 3];
        acc0 += G32_LOAD(s0); acc1 += G32_LOAD(s1); acc2 += G32_LOAD(s2); acc3 += G32_LOAD(s3);
        j += 4;
    }
    for (; j < end; ++j) acc0 += G32_LOAD(csr_src[j]);
    float r = ((acc0 + acc1) + (acc2 + acc3)) * dinv[d] + b[lane];
    out[(size_t)d * 32 + lane] = r;
}

extern "C" void kernel_launch(void* const* d_in, const int* in_sizes, int n_in,
                              void* d_out, int out_size, void* d_ws, size_t ws_size,
                              hipStream_t stream) {
    const float* x = (const float*)d_in[0];
    const int* ei = (const int*)d_in[1];
    const float* W1 = (const float*)d_in[2];
    const float* b1 = (const float*)d_in[3];
    const float* W2 = (const float*)d_in[4];
    const float* b2 = (const float*)d_in[5];

    const int N = in_sizes[0] / 128;  // 100000
    const int E = in_sizes[1] / 2;    // 1600000
    const int* src = ei;
    const int* dst = ei + E;
    const int nbk = NBKT(N);          // 782 buckets of 128 dst nodes

    // workspace layout (4-byte units unless noted)
    int* bcnt = (int*)d_ws;                            // nbk (pad 1024)
    int* boffs = bcnt + 1024;                          // nbk+1 (pad 1024)
    int* gcursor = boffs + 1024;                       // nbk (pad 1024)
    float* dinv = (float*)(gcursor + 1024);            // N
    int* offs = (int*)(dinv + ((N + 255) & ~255));     // N+1
    int* entries = offs + ((N + 1 + 255) & ~255);      // E
    int* csr_src = entries + ((E + 255) & ~255);       // E
    unsigned short* h1s = (unsigned short*)(csr_src + ((E + 255) & ~255));  // N*64 bf16
    unsigned short* h3s = h1s + (size_t)N * 64;        // N*32 bf16 (must NOT alias h1s)
    float* out = (float*)d_out;

    // 1) bucket histogram -> offsets
    hipMemsetAsync(bcnt, 0, 1024 * 4, stream);
    bhist_kernel<<<(E + BH_CHUNK - 1) / BH_CHUNK, 256, 0, stream>>>(dst, E, nbk, bcnt);
    bscan_kernel<<<1, 1024, 0, stream>>>(bcnt, nbk, E, boffs, gcursor);

    // 2) two-phase node-exact CSR build (bucket2csr also emits dinv)
    binfill_kernel<<<(E + BF_CHUNK - 1) / BF_CHUNK, 256, 0, stream>>>(src, dst, E, nbk, gcursor, entries);
    bucket2csr_kernel<<<nbk, 256, 0, stream>>>(entries, boffs, nbk, offs, csr_src, dinv, N, E);

    // 3) h1s = bf16((x @ W1) * dinv)
    gemm_tile_kernel<128, 64, 64, true><<<(N + 63) / 64, 256, 0, stream>>>(x, W1, dinv, h1s, N);

    // 4+5 fused) h3s = bf16((relu(dinv*gather(h1s)+b1) @ W2) * dinv)
    gather64_gemm2_kernel<<<(N + 3) / 4, 256, 0, stream>>>(h1s, dinv, offs, csr_src, b1, W2, h3s, N);

    // 6) out = dinv*(gather h3s) + b2   (fp32)
    gather32_kernel<<<(N + 7) / 8, 256, 0, stream>>>(h3s, dinv, offs, csr_src, b2, out, N);
}

// Round 17
// 203.039 us; speedup vs baseline: 1.0909x; 1.0871x over previous
//
#include <hip/hip_runtime.h>

// GCN 2-layer. R17: revert to R14 structure (proven 202.8us; R16 fusion cost
// occupancy and regressed). One change: h2 stored bf16 (gather64 writes bf16,
// gemm2 A-staging converts) -- saves the 25.6MB h2 round-trip's other half.

#define NBKT(n) (((n) + 127) >> 7)

__device__ inline float bf2f(unsigned short u) {
    union { unsigned int i; float f; } v;
    v.i = ((unsigned int)u) << 16;
    return v.f;
}
__device__ inline unsigned short f2bf(float f) {
    union { float f; unsigned int i; } v;
    v.f = f;
    unsigned int u = v.i;
    return (unsigned short)((u + 0x7fff + ((u >> 16) & 1)) >> 16);  // RTN-even
}

// ---------------- bucket histogram (R13 proven) ----------------
#define BH_CHUNK 4096
__global__ void __launch_bounds__(256) bhist_kernel(
        const int* __restrict__ dst, int E, int nbk, int* __restrict__ bcnt) {
    __shared__ int cnt[NBKT(100000)];
    const int t = threadIdx.x;
    const int beg = blockIdx.x * BH_CHUNK;
    const int end = min(E, beg + BH_CHUNK);
    for (int b = t; b < nbk; b += 256) cnt[b] = 0;
    __syncthreads();
    for (int i = beg + t; i < end; i += 256) atomicAdd(&cnt[dst[i] >> 7], 1);
    __syncthreads();
    for (int b = t; b < nbk; b += 256) {
        int c = cnt[b];
        if (c) atomicAdd(&bcnt[b], c);
    }
}

// ---------------- bucket offsets (R13 proven) ----------------
__global__ void bscan_kernel(const int* __restrict__ bcnt, int nbk, int E,
                             int* __restrict__ boffs, int* __restrict__ gcursor) {
    __shared__ int s[1024];
    const int t = threadIdx.x;
    int v = (t < nbk) ? bcnt[t] : 0;
    s[t] = v;
    __syncthreads();
    for (int off = 1; off < 1024; off <<= 1) {
        int x = (t >= off) ? s[t - off] : 0;
        __syncthreads();
        s[t] += x;
        __syncthreads();
    }
    if (t < nbk) {
        int excl = s[t] - v;
        boffs[t] = excl;
        gcursor[t] = excl;
    }
    if (t == 0) boffs[nbk] = E;
}

// ---------------- binfill (R8/R11 proven): entry = (src<<7)|(dst&127) ----------------
#define BF_CHUNK 4096
__global__ void __launch_bounds__(256) binfill_kernel(
        const int* __restrict__ src, const int* __restrict__ dst, int E, int nbk,
        int* __restrict__ gcursor, int* __restrict__ entries) {
    __shared__ int cnt[NBKT(100000)];
    __shared__ int gbase[NBKT(100000)];
    __shared__ int rank[NBKT(100000)];
    const int t = threadIdx.x;
    const int beg = blockIdx.x * BF_CHUNK;
    const int end = min(E, beg + BF_CHUNK);
    for (int b = t; b < nbk; b += 256) cnt[b] = 0;
    __syncthreads();
    for (int i = beg + t; i < end; i += 256) atomicAdd(&cnt[dst[i] >> 7], 1);
    __syncthreads();
    for (int b = t; b < nbk; b += 256) {
        int c = cnt[b];
        gbase[b] = c ? atomicAdd(&gcursor[b], c) : 0;
        rank[b] = 0;
    }
    __syncthreads();
    for (int i = beg + t; i < end; i += 256) {
        int d = dst[i];
        int b = d >> 7;
        int r = atomicAdd(&rank[b], 1);
        entries[gbase[b] + r] = (src[i] << 7) | (d & 127);
    }
}

// ---------------- bucket2csr (R9 proven) + dinv emission (R13) ----------------
__global__ void __launch_bounds__(256) bucket2csr_kernel(
        const int* __restrict__ entries, const int* __restrict__ boffs, int nbk,
        int* __restrict__ offs, int* __restrict__ csr_src, float* __restrict__ dinv,
        int N, int E) {
    __shared__ int cnt[128];
    __shared__ int s[128];
    __shared__ int rank[128];
    const int t = threadIdx.x;
    const int b = blockIdx.x;
    const int beg = boffs[b];
    const int end = boffs[b + 1];
    if (t < 128) { cnt[t] = 0; rank[t] = 0; }
    __syncthreads();
    for (int i = beg + t; i < end; i += 256) atomicAdd(&cnt[entries[i] & 127], 1);
    __syncthreads();
    if (t < 128) s[t] = cnt[t];
    __syncthreads();
    for (int off = 1; off < 128; off <<= 1) {
        int x = 0;
        if (t < 128 && t >= off) x = s[t - off];
        __syncthreads();
        if (t < 128) s[t] += x;
        __syncthreads();
    }
    const int node0 = b * 128;
    if (t < 128 && node0 + t < N) {
        offs[node0 + t] = beg + s[t] - cnt[t];
        dinv[node0 + t] = rsqrtf((float)cnt[t] + 1.0f);  // +1 = self-loop
    }
    if (b == 0 && t == 0) offs[N] = E;
    __syncthreads();
    for (int i = beg + t; i < end; i += 256) {
        int e = entries[i];
        int d = e & 127;
        int r = atomicAdd(&rank[d], 1);
        csr_src[beg + s[d] - cnt[d] + r] = (int)((unsigned)e >> 7);
    }
}

// ---------------- LDS-tiled GEMM (R6 proven), bf16 in/out options ----------------
#define FMA4(ACC, AV, WV) \
    ACC.x += (AV) * (WV).x; ACC.y += (AV) * (WV).y; ACC.z += (AV) * (WV).z; ACC.w += (AV) * (WV).w;

template <int K, int C, int BR, bool BF16OUT, bool BF16IN>
__global__ void __launch_bounds__(256) gemm_tile_kernel(
        const void* __restrict__ Av, const float* __restrict__ W,
        const float* __restrict__ dinv, void* __restrict__ outv, int N) {
    constexpr int F4R = K / 4;
    constexpr int CG = C / 4;
    static_assert(256 / CG * 4 == BR, "geometry");
    __shared__ float Wl[K * C];
    __shared__ float Al[BR * K];

    const int t = threadIdx.x;
    for (int i = t; i < K * C / 4; i += 256) ((float4*)Wl)[i] = ((const float4*)W)[i];
    const int row0 = blockIdx.x * BR;
    for (int i = t; i < BR * F4R; i += 256) {
        int r = i / F4R, k4 = i % F4R;
        float4 v = make_float4(0.f, 0.f, 0.f, 0.f);
        if (row0 + r < N) {
            if (BF16IN) {
                ushort4 u = ((const ushort4*)Av)[(size_t)(row0 + r) * F4R + k4];
                v.x = bf2f(u.x); v.y = bf2f(u.y); v.z = bf2f(u.z); v.w = bf2f(u.w);
            } else {
                v = ((const float4*)Av)[(size_t)(row0 + r) * F4R + k4];
            }
        }
        *(float4*)(Al + r * K + k4 * 4) = v;
    }
    __syncthreads();

    const int c0 = (t % CG) * 4;
    const int r0 = (t / CG) * 4;
    const float* Ab = Al + r0 * K;

    float4 acc0 = {0, 0, 0, 0}, acc1 = {0, 0, 0, 0}, acc2 = {0, 0, 0, 0}, acc3 = {0, 0, 0, 0};

#pragma unroll 2
    for (int k4 = 0; k4 < K / 4; ++k4) {
        float4 a0 = *(const float4*)(Ab + 0 * K + k4 * 4);
        float4 a1 = *(const float4*)(Ab + 1 * K + k4 * 4);
        float4 a2 = *(const float4*)(Ab + 2 * K + k4 * 4);
        float4 a3 = *(const float4*)(Ab + 3 * K + k4 * 4);
        float4 w0 = *(const float4*)(Wl + (k4 * 4 + 0) * C + c0);
        float4 w1 = *(const float4*)(Wl + (k4 * 4 + 1) * C + c0);
        float4 w2 = *(const float4*)(Wl + (k4 * 4 + 2) * C + c0);
        float4 w3 = *(const float4*)(Wl + (k4 * 4 + 3) * C + c0);
        FMA4(acc0, a0.x, w0) FMA4(acc1, a1.x, w0) FMA4(acc2, a2.x, w0) FMA4(acc3, a3.x, w0)
        FMA4(acc0, a0.y, w1) FMA4(acc1, a1.y, w1) FMA4(acc2, a2.y, w1) FMA4(acc3, a3.y, w1)
        FMA4(acc0, a0.z, w2) FMA4(acc1, a1.z, w2) FMA4(acc2, a2.z, w2) FMA4(acc3, a3.z, w2)
        FMA4(acc0, a0.w, w3) FMA4(acc1, a1.w, w3) FMA4(acc2, a2.w, w3) FMA4(acc3, a3.w, w3)
    }

    const int row = row0 + r0;
#pragma unroll
    for (int i = 0; i < 4; ++i) {
        int rr = row + i;
        if (rr < N) {
            float d = dinv[rr];
            float4 fr = (i == 0) ? acc0 : (i == 1) ? acc1 : (i == 2) ? acc2 : acc3;
            fr.x *= d; fr.y *= d; fr.z *= d; fr.w *= d;
            if (BF16OUT) {
                ushort4 o;
                o.x = f2bf(fr.x); o.y = f2bf(fr.y); o.z = f2bf(fr.z); o.w = f2bf(fr.w);
                *(ushort4*)((unsigned short*)outv + (size_t)rr * C + c0) = o;
            } else {
                *(float4*)((float*)outv + (size_t)rr * C + c0) = fr;
            }
        }
    }
}

// ---------------- gather C=64 (R14 proven): one node/wave, 16 edges in flight --------
// bf16 output (h2).
#define G64_LOAD(SS) bf2f(hs[(size_t)(SS) * 64 + lane])
__global__ void __launch_bounds__(256) gather64_kernel(
        const unsigned short* __restrict__ hs, const float* __restrict__ dinv,
        const int* __restrict__ offs, const int* __restrict__ csr_src,
        const float* __restrict__ b, unsigned short* __restrict__ out, int N) {
    const int lane = threadIdx.x & 63;
    const int d = blockIdx.x * 4 + (threadIdx.x >> 6);  // wave-uniform
    if (d >= N) return;
    const int beg = offs[d];
    const int end = offs[d + 1];
    float acc0 = G64_LOAD(d);  // self-loop
    float acc1 = 0.f, acc2 = 0.f, acc3 = 0.f;
    int j = beg;
    for (; j + 15 < end; j += 16) {
        int s0 = csr_src[j + 0], s1 = csr_src[j + 1], s2 = csr_src[j + 2], s3 = csr_src[j + 3];
        int s4 = csr_src[j + 4], s5 = csr_src[j + 5], s6 = csr_src[j + 6], s7 = csr_src[j + 7];
        int s8 = csr_src[j + 8], s9 = csr_src[j + 9], sa = csr_src[j + 10], sb = csr_src[j + 11];
        int sc = csr_src[j + 12], sd = csr_src[j + 13], se = csr_src[j + 14], sf = csr_src[j + 15];
        float v0 = G64_LOAD(s0), v1 = G64_LOAD(s1), v2 = G64_LOAD(s2), v3 = G64_LOAD(s3);
        float v4 = G64_LOAD(s4), v5 = G64_LOAD(s5), v6 = G64_LOAD(s6), v7 = G64_LOAD(s7);
        float v8 = G64_LOAD(s8), v9 = G64_LOAD(s9), va = G64_LOAD(sa), vb = G64_LOAD(sb);
        float vc = G64_LOAD(sc), vd = G64_LOAD(sd), ve = G64_LOAD(se), vf = G64_LOAD(sf);
        acc0 += v0; acc1 += v1; acc2 += v2; acc3 += v3;
        acc0 += v4; acc1 += v5; acc2 += v6; acc3 += v7;
        acc0 += v8; acc1 += v9; acc2 += va; acc3 += vb;
        acc0 += vc; acc1 += vd; acc2 += ve; acc3 += vf;
    }
    if (j + 7 < end) {
        int s0 = csr_src[j + 0], s1 = csr_src[j + 1], s2 = csr_src[j + 2], s3 = csr_src[j + 3];
        int s4 = csr_src[j + 4], s5 = csr_src[j + 5], s6 = csr_src[j + 6], s7 = csr_src[j + 7];
        float v0 = G64_LOAD(s0), v1 = G64_LOAD(s1), v2 = G64_LOAD(s2), v3 = G64_LOAD(s3);
        float v4 = G64_LOAD(s4), v5 = G64_LOAD(s5), v6 = G64_LOAD(s6), v7 = G64_LOAD(s7);
        acc0 += v0; acc1 += v1; acc2 += v2; acc3 += v3;
        acc0 += v4; acc1 += v5; acc2 += v6; acc3 += v7;
        j += 8;
    }
    if (j + 3 < end) {
        int s0 = csr_src[j + 0], s1 = csr_src[j + 1], s2 = csr_src[j + 2], s3 = csr_src[j + 3];
        acc0 += G64_LOAD(s0); acc1 += G64_LOAD(s1); acc2 += G64_LOAD(s2); acc3 += G64_LOAD(s3);
        j += 4;
    }
    for (; j < end; ++j) acc0 += G64_LOAD(csr_src[j]);
    float r = ((acc0 + acc1) + (acc2 + acc3)) * dinv[d] + b[lane];
    r = fmaxf(r, 0.f);  // relu (layer 1)
    out[(size_t)d * 64 + lane] = f2bf(r);
}

// ---------------- gather C=32 (R14 proven): 2 nodes/wave, 16 edges in flight ---------
#define G32_LOAD(SS) bf2f(hs[(size_t)(SS) * 32 + lane])
__global__ void __launch_bounds__(256) gather32_kernel(
        const unsigned short* __restrict__ hs, const float* __restrict__ dinv,
        const int* __restrict__ offs, const int* __restrict__ csr_src,
        const float* __restrict__ b, float* __restrict__ out, int N) {
    const int lane = threadIdx.x & 31;
    const int d = blockIdx.x * 8 + (threadIdx.x >> 5);
    if (d >= N) return;
    const int beg = offs[d];
    const int end = offs[d + 1];
    float acc0 = G32_LOAD(d);  // self-loop
    float acc1 = 0.f, acc2 = 0.f, acc3 = 0.f;
    int j = beg;
    for (; j + 15 < end; j += 16) {
        int s0 = csr_src[j + 0], s1 = csr_src[j + 1], s2 = csr_src[j + 2], s3 = csr_src[j + 3];
        int s4 = csr_src[j + 4], s5 = csr_src[j + 5], s6 = csr_src[j + 6], s7 = csr_src[j + 7];
        int s8 = csr_src[j + 8], s9 = csr_src[j + 9], sa = csr_src[j + 10], sb = csr_src[j + 11];
        int sc = csr_src[j + 12], sd = csr_src[j + 13], se = csr_src[j + 14], sf = csr_src[j + 15];
        float v0 = G32_LOAD(s0), v1 = G32_LOAD(s1), v2 = G32_LOAD(s2), v3 = G32_LOAD(s3);
        float v4 = G32_LOAD(s4), v5 = G32_LOAD(s5), v6 = G32_LOAD(s6), v7 = G32_LOAD(s7);
        float v8 = G32_LOAD(s8), v9 = G32_LOAD(s9), va = G32_LOAD(sa), vb = G32_LOAD(sb);
        float vc = G32_LOAD(sc), vd = G32_LOAD(sd), ve = G32_LOAD(se), vf = G32_LOAD(sf);
        acc0 += v0; acc1 += v1; acc2 += v2; acc3 += v3;
        acc0 += v4; acc1 += v5; acc2 += v6; acc3 += v7;
        acc0 += v8; acc1 += v9; acc2 += va; acc3 += vb;
        acc0 += vc; acc1 += vd; acc2 += ve; acc3 += vf;
    }
    if (j + 7 < end) {
        int s0 = csr_src[j + 0], s1 = csr_src[j + 1], s2 = csr_src[j + 2], s3 = csr_src[j + 3];
        int s4 = csr_src[j + 4], s5 = csr_src[j + 5], s6 = csr_src[j + 6], s7 = csr_src[j + 7];
        float v0 = G32_LOAD(s0), v1 = G32_LOAD(s1), v2 = G32_LOAD(s2), v3 = G32_LOAD(s3);
        float v4 = G32_LOAD(s4), v5 = G32_LOAD(s5), v6 = G32_LOAD(s6), v7 = G32_LOAD(s7);
        acc0 += v0; acc1 += v1; acc2 += v2; acc3 += v3;
        acc0 += v4; acc1 += v5; acc2 += v6; acc3 += v7;
        j += 8;
    }
    if (j + 3 < end) {
        int s0 = csr_src[j + 0], s1 = csr_src[j + 1], s2 = csr_src[j + 2], s3 = csr_src[j + 3];
        acc0 += G32_LOAD(s0); acc1 += G32_LOAD(s1); acc2 += G32_LOAD(s2); acc3 += G32_LOAD(s3);
        j += 4;
    }
    for (; j < end; ++j) acc0 += G32_LOAD(csr_src[j]);
    float r = ((acc0 + acc1) + (acc2 + acc3)) * dinv[d] + b[lane];
    out[(size_t)d * 32 + lane] = r;
}

extern "C" void kernel_launch(void* const* d_in, const int* in_sizes, int n_in,
                              void* d_out, int out_size, void* d_ws, size_t ws_size,
                              hipStream_t stream) {
    const float* x = (const float*)d_in[0];
    const int* ei = (const int*)d_in[1];
    const float* W1 = (const float*)d_in[2];
    const float* b1 = (const float*)d_in[3];
    const float* W2 = (const float*)d_in[4];
    const float* b2 = (const float*)d_in[5];

    const int N = in_sizes[0] / 128;  // 100000
    const int E = in_sizes[1] / 2;    // 1600000
    const int* src = ei;
    const int* dst = ei + E;
    const int nbk = NBKT(N);          // 782 buckets of 128 dst nodes

    // workspace layout (4-byte units unless noted)
    int* bcnt = (int*)d_ws;                            // nbk (pad 1024)
    int* boffs = bcnt + 1024;                          // nbk+1 (pad 1024)
    int* gcursor = boffs + 1024;                       // nbk (pad 1024)
    float* dinv = (float*)(gcursor + 1024);            // N
    int* offs = (int*)(dinv + ((N + 255) & ~255));     // N+1
    int* entries = offs + ((N + 1 + 255) & ~255);      // E
    int* csr_src = entries + ((E + 255) & ~255);       // E
    unsigned short* h1s = (unsigned short*)(csr_src + ((E + 255) & ~255));  // N*64 bf16
    unsigned short* h2b = h1s + (size_t)N * 64;        // N*64 bf16
    unsigned short* h3s = h1s;                         // reuse h1s region (N*32 bf16)
    float* out = (float*)d_out;

    // 1) bucket histogram -> offsets
    hipMemsetAsync(bcnt, 0, 1024 * 4, stream);
    bhist_kernel<<<(E + BH_CHUNK - 1) / BH_CHUNK, 256, 0, stream>>>(dst, E, nbk, bcnt);
    bscan_kernel<<<1, 1024, 0, stream>>>(bcnt, nbk, E, boffs, gcursor);

    // 2) two-phase node-exact CSR build (bucket2csr also emits dinv)
    binfill_kernel<<<(E + BF_CHUNK - 1) / BF_CHUNK, 256, 0, stream>>>(src, dst, E, nbk, gcursor, entries);
    bucket2csr_kernel<<<nbk, 256, 0, stream>>>(entries, boffs, nbk, offs, csr_src, dinv, N, E);

    // 3) h1s = bf16((x @ W1) * dinv)
    gemm_tile_kernel<128, 64, 64, true, false><<<(N + 63) / 64, 256, 0, stream>>>(x, W1, dinv, h1s, N);

    // 4) h2b = bf16(relu(dinv*(gather h1s) + b1))
    gather64_kernel<<<(N + 3) / 4, 256, 0, stream>>>(h1s, dinv, offs, csr_src, b1, h2b, N);

    // 5) h3s = bf16((h2b @ W2) * dinv)   (bf16 A input)
    gemm_tile_kernel<64, 32, 128, true, true><<<(N + 127) / 128, 256, 0, stream>>>(h2b, W2, dinv, h3s, N);

    // 6) out = dinv*(gather h3s) + b2   (fp32)
    gather32_kernel<<<(N + 7) / 8, 256, 0, stream>>>(h3s, dinv, offs, csr_src, b2, out, N);
}